// Round 14
// baseline (287.958 us; speedup 1.0000x reference)
//
#include <hip/hip_runtime.h>
#include <math.h>

#define NB 32768
#define ND 768
#define NH 256
#define NG 8
#define GSZ 96

typedef __attribute__((ext_vector_type(8))) short short8_t;
typedef __attribute__((ext_vector_type(4))) float f32x4;

__device__ __forceinline__ float gelu_exact(float v) {
    return 0.5f * v * (1.0f + erff(v * 0.7071067811865475f));
}
__device__ __forceinline__ float sigmoidf_(float v) {
    return 1.0f / (1.0f + expf(-v));
}
__device__ __forceinline__ unsigned short f2bf(float f) {
    union { float f; unsigned u; } a; a.f = f;
    unsigned r = a.u + 0x7FFF + ((a.u >> 16) & 1);
    return (unsigned short)(r >> 16);
}
__device__ __forceinline__ void f2bf2(float f, unsigned short& hi, unsigned short& lo) {
    union { float f; unsigned u; } a; a.f = f;
    unsigned r = a.u + 0x7FFF + ((a.u >> 16) & 1);
    hi = (unsigned short)(r >> 16);
    union { unsigned u; float f; } hf; hf.u = (r >> 16) << 16;
    float rem = f - hf.f;
    union { float f; unsigned u; } b; b.f = rem;
    unsigned r2 = b.u + 0x7FFF + ((b.u >> 16) & 1);
    lo = (unsigned short)(r2 >> 16);
}

// ---------------------------------------------------------------------------
// cvt_wall: weight conversions + scalar zeroing (unchanged).
// ---------------------------------------------------------------------------
__global__ __launch_bounds__(256) void cvt_wall(
    const float* __restrict__ w1, const float* __restrict__ dw1,
    const float* __restrict__ dw2, const float* __restrict__ w2,
    unsigned short* __restrict__ w1Th, unsigned short* __restrict__ w1Tl,
    unsigned short* __restrict__ dw1T, unsigned short* __restrict__ dw2T,
    unsigned short* __restrict__ w2Th, unsigned short* __restrict__ w2Tl,
    float* __restrict__ scal)
{
    const int b = blockIdx.x, t = threadIdx.x;
    if (b < 96) {
        int idx = b * 256 + t;
        int k8 = idx >> 8, c = idx & 255;
        short8_t h, lo;
        #pragma unroll
        for (int j = 0; j < 8; ++j) {
            unsigned short hi_, lo_;
            f2bf2(w1[(size_t)(k8 * 8 + j) * 256 + c], hi_, lo_);
            h[j] = (short)hi_; lo[j] = (short)lo_;
        }
        *(short8_t*)(w1Th + (size_t)c * 768 + k8 * 8) = h;
        *(short8_t*)(w1Tl + (size_t)c * 768 + k8 * 8) = lo;
    } else if (b < 192) {
        int idx = (b - 96) * 256 + t;
        int k8 = idx >> 8, c = idx & 255;
        short8_t h;
        #pragma unroll
        for (int j = 0; j < 8; ++j)
            h[j] = (short)f2bf(dw1[(size_t)(k8 * 8 + j) * 256 + c]);
        *(short8_t*)(dw1T + (size_t)c * 768 + k8 * 8) = h;
    } else if (b < 288) {
        int idx = (b - 192) * 256 + t;
        int k8 = idx / 768, c = idx - k8 * 768;
        short8_t h;
        #pragma unroll
        for (int j = 0; j < 8; ++j)
            h[j] = (short)f2bf(dw2[(size_t)(k8 * 8 + j) * 768 + c]);
        *(short8_t*)(dw2T + (size_t)c * 256 + k8 * 8) = h;
    } else if (b < 304) {
        int idx = (b - 288) * 256 + t;
        int k8 = idx >> 7, c = idx & 127;
        short8_t h, lo;
        #pragma unroll
        for (int j = 0; j < 8; ++j) {
            unsigned short hi_, lo_;
            f2bf2(w2[(size_t)(k8 * 8 + j) * 128 + c], hi_, lo_);
            h[j] = (short)hi_; lo[j] = (short)lo_;
        }
        *(short8_t*)(w2Th + (size_t)c * 256 + k8 * 8) = h;
        *(short8_t*)(w2Tl + (size_t)c * 256 + k8 * 8) = lo;
    } else {
        if (t < 11) scal[t] = 0.0f;
    }
}

// ---------------------------------------------------------------------------
// mfma_u1: u1 = x @ w1 (split-3 bf16 MFMA), f32 out, no bias.
// ROUND-12 geometry (proven best): 256 thr = 4 waves (2x2), tile 128x128,
// grid 512 (2 col-blocks) -> 2 blocks/CU for staging-stall overlap.
// ---------------------------------------------------------------------------
__global__ __launch_bounds__(256) void mfma_u1(
    const float* __restrict__ x, const unsigned short* __restrict__ BTh,
    const unsigned short* __restrict__ BTl, float* __restrict__ u1)
{
    __shared__ unsigned short Ah[128][40];
    __shared__ unsigned short Al[128][40];
    __shared__ unsigned short Bh[128][40];
    __shared__ unsigned short Bl[128][40];

    const int tid = threadIdx.x;
    const int l = tid & 63;
    const int w = tid >> 6;
    const int wm = w >> 1, wn = w & 1;
    const int lg = l >> 4, lr = l & 15;
    const int rb = blockIdx.x >> 1;
    const int cb = blockIdx.x & 1;
    const int rowsBase = rb * 128, colBase = cb * 128;

    f32x4 acc[4][4];
    #pragma unroll
    for (int mi = 0; mi < 4; ++mi)
        #pragma unroll
        for (int ni = 0; ni < 4; ++ni) acc[mi][ni] = (f32x4){0.f, 0.f, 0.f, 0.f};

    for (int kb = 0; kb < ND; kb += 32) {
        #pragma unroll
        for (int m = 0; m < 2; ++m) {
            int flat = m * 256 + tid;
            int row = flat >> 2, seg = flat & 3;
            const float* src = x + (size_t)(rowsBase + row) * ND + kb + seg * 8;
            float4 v0 = *(const float4*)src;
            float4 v1 = *(const float4*)(src + 4);
            float f[8] = {v0.x, v0.y, v0.z, v0.w, v1.x, v1.y, v1.z, v1.w};
            short8_t ph, pl;
            #pragma unroll
            for (int j = 0; j < 8; ++j) {
                unsigned short hi_, lo_;
                f2bf2(f[j], hi_, lo_);
                ph[j] = (short)hi_; pl[j] = (short)lo_;
            }
            *(short8_t*)&Ah[row][seg * 8] = ph;
            *(short8_t*)&Al[row][seg * 8] = pl;
        }
        #pragma unroll
        for (int m = 0; m < 2; ++m) {
            int flat = m * 256 + tid;
            int col = flat >> 2, seg = flat & 3;
            size_t off = (size_t)(colBase + col) * ND + kb + seg * 8;
            *(short8_t*)&Bh[col][seg * 8] = *(const short8_t*)(BTh + off);
            *(short8_t*)&Bl[col][seg * 8] = *(const short8_t*)(BTl + off);
        }
        __syncthreads();

        short8_t afh[4], afl[4], bfh[4], bfl[4];
        #pragma unroll
        for (int mi = 0; mi < 4; ++mi) {
            afh[mi] = *(const short8_t*)&Ah[wm * 64 + mi * 16 + lr][lg * 8];
            afl[mi] = *(const short8_t*)&Al[wm * 64 + mi * 16 + lr][lg * 8];
        }
        #pragma unroll
        for (int ni = 0; ni < 4; ++ni) {
            bfh[ni] = *(const short8_t*)&Bh[wn * 64 + ni * 16 + lr][lg * 8];
            bfl[ni] = *(const short8_t*)&Bl[wn * 64 + ni * 16 + lr][lg * 8];
        }
        #pragma unroll
        for (int mi = 0; mi < 4; ++mi)
            #pragma unroll
            for (int ni = 0; ni < 4; ++ni) {
                acc[mi][ni] = __builtin_amdgcn_mfma_f32_16x16x32_bf16(
                    afl[mi], bfh[ni], acc[mi][ni], 0, 0, 0);
                acc[mi][ni] = __builtin_amdgcn_mfma_f32_16x16x32_bf16(
                    afh[mi], bfl[ni], acc[mi][ni], 0, 0, 0);
                acc[mi][ni] = __builtin_amdgcn_mfma_f32_16x16x32_bf16(
                    afh[mi], bfh[ni], acc[mi][ni], 0, 0, 0);
            }
        __syncthreads();
    }

    #pragma unroll
    for (int ni = 0; ni < 4; ++ni) {
        int col = colBase + wn * 64 + ni * 16 + lr;
        #pragma unroll
        for (int mi = 0; mi < 4; ++mi) {
            int rbase = rowsBase + wm * 64 + mi * 16 + lg * 4;
            #pragma unroll
            for (int j = 0; j < 4; ++j)
                u1[(size_t)(rbase + j) * 256 + col] = acc[mi][ni][j];
        }
    }
}

// ---------------------------------------------------------------------------
// k1_epi: h1 = gelu(LN(u1 + b1)); one wave per row (unchanged)
// ---------------------------------------------------------------------------
__global__ __launch_bounds__(256) void k1_epi(
    const float* __restrict__ u1, const float* __restrict__ b1,
    const float* __restrict__ lng, const float* __restrict__ lnb,
    float* __restrict__ h1)
{
    const int wv = threadIdx.x >> 6, l = threadIdx.x & 63;
    const int row = blockIdx.x * 4 + wv;
    float4 a = *(const float4*)(u1 + (size_t)row * 256 + l * 4);
    float4 bb = *(const float4*)(b1 + l * 4);
    float u[4] = {a.x + bb.x, a.y + bb.y, a.z + bb.z, a.w + bb.w};
    float s = u[0] + u[1] + u[2] + u[3];
    float q = u[0]*u[0] + u[1]*u[1] + u[2]*u[2] + u[3]*u[3];
    #pragma unroll
    for (int o = 1; o < 64; o <<= 1) {
        s += __shfl_xor(s, o);
        q += __shfl_xor(q, o);
    }
    float mean = s * (1.0f / 256.0f);
    float var  = q * (1.0f / 256.0f) - mean * mean;
    float rstd = rsqrtf(var + 1e-5f);
    float4 g = *(const float4*)(lng + l * 4);
    float4 be = *(const float4*)(lnb + l * 4);
    float4 o;
    o.x = gelu_exact((u[0] - mean) * rstd * g.x + be.x);
    o.y = gelu_exact((u[1] - mean) * rstd * g.y + be.y);
    o.z = gelu_exact((u[2] - mean) * rstd * g.z + be.z);
    o.w = gelu_exact((u[3] - mean) * rstd * g.w + be.w);
    *(float4*)(h1 + (size_t)row * 256 + l * 4) = o;
}

// ---------------------------------------------------------------------------
// mfma_u2: u2 = h1 @ w2 (split-3), f32 out, no bias (unchanged)
// ---------------------------------------------------------------------------
__global__ __launch_bounds__(256) void mfma_u2(
    const float* __restrict__ h1, const unsigned short* __restrict__ BTh,
    const unsigned short* __restrict__ BTl, float* __restrict__ u2)
{
    __shared__ unsigned short Ah[128][40];
    __shared__ unsigned short Al[128][40];
    __shared__ unsigned short Bh[128][40];
    __shared__ unsigned short Bl[128][40];

    const int tid = threadIdx.x;
    const int l = tid & 63;
    const int w = tid >> 6;
    const int wm = w >> 1, wn = w & 1;
    const int lg = l >> 4, lr = l & 15;
    const int rowsBase = blockIdx.x * 128;

    f32x4 acc[4][4];
    #pragma unroll
    for (int mi = 0; mi < 4; ++mi)
        #pragma unroll
        for (int ni = 0; ni < 4; ++ni) acc[mi][ni] = (f32x4){0.f, 0.f, 0.f, 0.f};

    for (int kb = 0; kb < 256; kb += 32) {
        #pragma unroll
        for (int m = 0; m < 2; ++m) {
            int flat = m * 256 + tid;
            int row = flat >> 2, seg = flat & 3;
            const float* src = h1 + (size_t)(rowsBase + row) * 256 + kb + seg * 8;
            float4 v0 = *(const float4*)src;
            float4 v1 = *(const float4*)(src + 4);
            float f[8] = {v0.x, v0.y, v0.z, v0.w, v1.x, v1.y, v1.z, v1.w};
            short8_t ph, pl;
            #pragma unroll
            for (int j = 0; j < 8; ++j) {
                unsigned short hi_, lo_;
                f2bf2(f[j], hi_, lo_);
                ph[j] = (short)hi_; pl[j] = (short)lo_;
            }
            *(short8_t*)&Ah[row][seg * 8] = ph;
            *(short8_t*)&Al[row][seg * 8] = pl;
        }
        #pragma unroll
        for (int m = 0; m < 2; ++m) {
            int flat = m * 256 + tid;
            int col = flat >> 2, seg = flat & 3;
            size_t off = (size_t)col * 256 + kb + seg * 8;
            *(short8_t*)&Bh[col][seg * 8] = *(const short8_t*)(BTh + off);
            *(short8_t*)&Bl[col][seg * 8] = *(const short8_t*)(BTl + off);
        }
        __syncthreads();

        short8_t afh[4], afl[4], bfh[4], bfl[4];
        #pragma unroll
        for (int mi = 0; mi < 4; ++mi) {
            afh[mi] = *(const short8_t*)&Ah[wm * 64 + mi * 16 + lr][lg * 8];
            afl[mi] = *(const short8_t*)&Al[wm * 64 + mi * 16 + lr][lg * 8];
        }
        #pragma unroll
        for (int ni = 0; ni < 4; ++ni) {
            bfh[ni] = *(const short8_t*)&Bh[wn * 64 + ni * 16 + lr][lg * 8];
            bfl[ni] = *(const short8_t*)&Bl[wn * 64 + ni * 16 + lr][lg * 8];
        }
        #pragma unroll
        for (int mi = 0; mi < 4; ++mi)
            #pragma unroll
            for (int ni = 0; ni < 4; ++ni) {
                acc[mi][ni] = __builtin_amdgcn_mfma_f32_16x16x32_bf16(
                    afl[mi], bfh[ni], acc[mi][ni], 0, 0, 0);
                acc[mi][ni] = __builtin_amdgcn_mfma_f32_16x16x32_bf16(
                    afh[mi], bfl[ni], acc[mi][ni], 0, 0, 0);
                acc[mi][ni] = __builtin_amdgcn_mfma_f32_16x16x32_bf16(
                    afh[mi], bfh[ni], acc[mi][ni], 0, 0, 0);
            }
        __syncthreads();
    }

    #pragma unroll
    for (int ni = 0; ni < 4; ++ni) {
        int col = wn * 64 + ni * 16 + lr;
        #pragma unroll
        for (int mi = 0; mi < 4; ++mi) {
            int rbase = rowsBase + wm * 64 + mi * 16 + lg * 4;
            #pragma unroll
            for (int j = 0; j < 4; ++j)
                u2[(size_t)(rbase + j) * 128 + col] = acc[mi][ni][j];
        }
    }
}

// ---------------------------------------------------------------------------
// mfma_hi<ACT, AF32>: out = act(A @ BT^T + bias), hi-only bf16 MFMA (unchanged)
// ---------------------------------------------------------------------------
template<int ACT, int AF32>
__global__ __launch_bounds__(256) void mfma_hi(
    const void* __restrict__ Ap, const unsigned short* __restrict__ BT,
    const float* __restrict__ bias, void* __restrict__ outp,
    int N, int K, int colBlocks)
{
    __shared__ unsigned short As[128][40];
    __shared__ unsigned short Bs[128][40];

    const int tid = threadIdx.x;
    const int l = tid & 63;
    const int w = tid >> 6;
    const int wm = w >> 1, wn = w & 1;
    const int lg = l >> 4, lr = l & 15;
    const int rb = blockIdx.x / colBlocks;
    const int cb = blockIdx.x - rb * colBlocks;
    const int rowsBase = rb * 128, colBase = cb * 128;

    f32x4 acc[4][4];
    #pragma unroll
    for (int mi = 0; mi < 4; ++mi)
        #pragma unroll
        for (int ni = 0; ni < 4; ++ni) acc[mi][ni] = (f32x4){0.f, 0.f, 0.f, 0.f};

    for (int kb = 0; kb < K; kb += 32) {
        if (AF32) {
            const float* A = (const float*)Ap;
            #pragma unroll
            for (int m = 0; m < 2; ++m) {
                int flat = m * 256 + tid;
                int row = flat >> 2, seg = flat & 3;
                const float* src = A + (size_t)(rowsBase + row) * K + kb + seg * 8;
                float4 v0 = *(const float4*)src;
                float4 v1 = *(const float4*)(src + 4);
                float f[8] = {v0.x, v0.y, v0.z, v0.w, v1.x, v1.y, v1.z, v1.w};
                short8_t h;
                #pragma unroll
                for (int j = 0; j < 8; ++j) h[j] = (short)f2bf(f[j]);
                *(short8_t*)&As[row][seg * 8] = h;
            }
        } else {
            const unsigned short* A = (const unsigned short*)Ap;
            #pragma unroll
            for (int m = 0; m < 2; ++m) {
                int flat = m * 256 + tid;
                int row = flat >> 2, seg = flat & 3;
                *(short8_t*)&As[row][seg * 8] =
                    *(const short8_t*)(A + (size_t)(rowsBase + row) * K + kb + seg * 8);
            }
        }
        #pragma unroll
        for (int m = 0; m < 2; ++m) {
            int flat = m * 256 + tid;
            int col = flat >> 2, seg = flat & 3;
            *(short8_t*)&Bs[col][seg * 8] =
                *(const short8_t*)(BT + (size_t)(colBase + col) * K + kb + seg * 8);
        }
        __syncthreads();

        short8_t af[4], bf[4];
        #pragma unroll
        for (int mi = 0; mi < 4; ++mi)
            af[mi] = *(const short8_t*)&As[wm * 64 + mi * 16 + lr][lg * 8];
        #pragma unroll
        for (int ni = 0; ni < 4; ++ni)
            bf[ni] = *(const short8_t*)&Bs[wn * 64 + ni * 16 + lr][lg * 8];
        #pragma unroll
        for (int mi = 0; mi < 4; ++mi)
            #pragma unroll
            for (int ni = 0; ni < 4; ++ni)
                acc[mi][ni] = __builtin_amdgcn_mfma_f32_16x16x32_bf16(
                    af[mi], bf[ni], acc[mi][ni], 0, 0, 0);
        __syncthreads();
    }

    #pragma unroll
    for (int ni = 0; ni < 4; ++ni) {
        int col = colBase + wn * 64 + ni * 16 + lr;
        float bv = bias[col];
        #pragma unroll
        for (int mi = 0; mi < 4; ++mi) {
            int rbase = rowsBase + wm * 64 + mi * 16 + lg * 4;
            #pragma unroll
            for (int j = 0; j < 4; ++j) {
                float v = acc[mi][ni][j] + bv;
                if (ACT == 0) {
                    ((unsigned short*)outp)[(size_t)(rbase + j) * N + col] =
                        f2bf(gelu_exact(v));
                } else {
                    ((float*)outp)[(size_t)(rbase + j) * N + col] = sigmoidf_(v);
                }
            }
        }
    }
}

// ---------------------------------------------------------------------------
// k3: h2 = gelu(u2+b2) in-reg; logits; probs; selection -> sel; scalars
// (unchanged)
// ---------------------------------------------------------------------------
__global__ __launch_bounds__(128) void k3_router(
    const float* __restrict__ u2, const float* __restrict__ w3,
    const float* __restrict__ b3, const float* __restrict__ gi,
    const float* __restrict__ b2, float* __restrict__ probsOut,
    float* __restrict__ selOut, float* __restrict__ scal)
{
    __shared__ float ws3[128][8];
    __shared__ float sAct[2], sP[2], sCnt[2][8];

    const int tid = threadIdx.x;
    *(float4*)&ws3[tid][0] = *(const float4*)(w3 + tid * 8);
    *(float4*)&ws3[tid][4] = *(const float4*)(w3 + tid * 8 + 4);
    __syncthreads();

    const int row = blockIdx.x * 128 + tid;
    const float* r0p = u2 + (size_t)row * 128;

    float accg[8];
    #pragma unroll
    for (int g = 0; g < 8; ++g) accg[g] = 0.0f;
    #pragma unroll 4
    for (int k4 = 0; k4 < 32; ++k4) {
        float4 a = *(const float4*)(r0p + k4 * 4);
        float4 bb = *(const float4*)(b2 + k4 * 4);
        float hv4[4];
        hv4[0] = gelu_exact(a.x + bb.x);
        hv4[1] = gelu_exact(a.y + bb.y);
        hv4[2] = gelu_exact(a.z + bb.z);
        hv4[3] = gelu_exact(a.w + bb.w);
        #pragma unroll
        for (int t = 0; t < 4; ++t)
            #pragma unroll
            for (int g = 0; g < 8; ++g)
                accg[g] = fmaf(hv4[t], ws3[k4 * 4 + t][g], accg[g]);
    }

    float p[8], gs[8], cnt[8];
    float actCnt = 0.0f, pSum = 0.0f;
    #pragma unroll
    for (int g = 0; g < 8; ++g) {
        float lg = accg[g] + b3[g] + gi[g];
        p[g] = sigmoidf_(lg);
    }
    #pragma unroll
    for (int g = 0; g < 8; ++g) {
        int rank = 0;
        #pragma unroll
        for (int j = 0; j < 8; ++j) {
            rank += (p[j] > p[g]) ? 1 : 0;
            rank += (j < g && p[j] == p[g]) ? 1 : 0;
        }
        float act = (rank < 2) ? 1.0f
                  : ((rank < 6) ? ((p[g] > 0.5f) ? 1.0f : 0.0f) : 0.0f);
        gs[g] = (act - p[g]) + p[g];
        float over = (p[g] > 0.5f) ? 1.0f : 0.0f;
        cnt[g] = over;
        actCnt += over;
        pSum += p[g];
    }

    *(float4*)(probsOut + (size_t)row * 8)     = *(float4*)&p[0];
    *(float4*)(probsOut + (size_t)row * 8 + 4) = *(float4*)&p[4];
    *(float4*)(selOut   + (size_t)row * 8)     = *(float4*)&gs[0];
    *(float4*)(selOut   + (size_t)row * 8 + 4) = *(float4*)&gs[4];

    #pragma unroll
    for (int o = 32; o > 0; o >>= 1) {
        actCnt += __shfl_down(actCnt, o);
        pSum   += __shfl_down(pSum, o);
        #pragma unroll
        for (int g = 0; g < 8; ++g) cnt[g] += __shfl_down(cnt[g], o);
    }
    if ((tid & 63) == 0) {
        int w = tid >> 6;
        sAct[w] = actCnt; sP[w] = pSum;
        #pragma unroll
        for (int g = 0; g < 8; ++g) sCnt[w][g] = cnt[g];
    }
    __syncthreads();
    if (tid == 0) {
        const float invB = 1.0f / 32768.0f;
        atomicAdd(&scal[0], (sAct[0] + sAct[1]) * invB);
        atomicAdd(&scal[9], (sP[0] + sP[1]) * invB);
        #pragma unroll
        for (int g = 0; g < 8; ++g)
            atomicAdd(&scal[1 + g], (sCnt[0][g] + sCnt[1][g]) * invB);
    }
}

// ---------------------------------------------------------------------------
// mfma_dw2m: dwts = sigmoid(g1h @ dw2 + db2), mask = sel_rep * dwts,
// active_dims count, and (ws path) gmask = sel_rep. 512 thr, tile 128x256.
// ---------------------------------------------------------------------------
__global__ __launch_bounds__(512) void mfma_dw2m(
    const unsigned short* __restrict__ g1h, const unsigned short* __restrict__ dw2T,
    const float* __restrict__ db2, const float* __restrict__ sel,
    float* __restrict__ dwts, float* __restrict__ maskOut,
    float* __restrict__ gmaskOut, float* __restrict__ activeDims)
{
    __shared__ unsigned short As[128][40];
    __shared__ unsigned short Bs[256][40];
    __shared__ float sc[8];

    const int tid = threadIdx.x;
    const int l = tid & 63;
    const int w = tid >> 6;
    const int wm = w >> 2, wn = w & 3;
    const int lg = l >> 4, lr = l & 15;
    const int rb = blockIdx.x / 3, cb = blockIdx.x - rb * 3;
    const int rowsBase = rb * 128, colBase = cb * 256;

    f32x4 acc[4][4];
    #pragma unroll
    for (int mi = 0; mi < 4; ++mi)
        #pragma unroll
        for (int ni = 0; ni < 4; ++ni) acc[mi][ni] = (f32x4){0.f, 0.f, 0.f, 0.f};

    const int sArow = tid >> 2, sAseg = tid & 3;

    for (int kb = 0; kb < 256; kb += 32) {
        *(short8_t*)&As[sArow][sAseg * 8] =
            *(const short8_t*)(g1h + (size_t)(rowsBase + sArow) * 256 + kb + sAseg * 8);
        #pragma unroll
        for (int m = 0; m < 2; ++m) {
            int flat = m * 512 + tid;
            int col = flat >> 2, seg = flat & 3;
            *(short8_t*)&Bs[col][seg * 8] =
                *(const short8_t*)(dw2T + (size_t)(colBase + col) * 256 + kb + seg * 8);
        }
        __syncthreads();

        short8_t af[4], bf[4];
        #pragma unroll
        for (int mi = 0; mi < 4; ++mi)
            af[mi] = *(const short8_t*)&As[wm * 64 + mi * 16 + lr][lg * 8];
        #pragma unroll
        for (int ni = 0; ni < 4; ++ni)
            bf[ni] = *(const short8_t*)&Bs[wn * 64 + ni * 16 + lr][lg * 8];
        #pragma unroll
        for (int mi = 0; mi < 4; ++mi)
            #pragma unroll
            for (int ni = 0; ni < 4; ++ni)
                acc[mi][ni] = __builtin_amdgcn_mfma_f32_16x16x32_bf16(
                    af[mi], bf[ni], acc[mi][ni], 0, 0, 0);
        __syncthreads();
    }

    float cntF = 0.0f;
    #pragma unroll
    for (int ni = 0; ni < 4; ++ni) {
        int col = colBase + wn * 64 + ni * 16 + lr;
        float bv = db2[col];
        int g = col / GSZ;
        #pragma unroll
        for (int mi = 0; mi < 4; ++mi) {
            int rbase = rowsBase + wm * 64 + mi * 16 + lg * 4;
            #pragma unroll
            for (int j = 0; j < 4; ++j) {
                int row = rbase + j;
                float sv = sel[(size_t)row * 8 + g];
                float v = sigmoidf_(acc[mi][ni][j] + bv);
                dwts[(size_t)row * 768 + col] = v;
                float m = sv * v;
                maskOut[(size_t)row * 768 + col] = m;
                if (gmaskOut) gmaskOut[(size_t)row * 768 + col] = sv;
                cntF += (m > 0.5f) ? 1.0f : 0.0f;
            }
        }
    }
    #pragma unroll
    for (int o = 32; o > 0; o >>= 1) cntF += __shfl_down(cntF, o);
    if ((tid & 63) == 0) sc[tid >> 6] = cntF;
    __syncthreads();
    if (tid == 0)
        atomicAdd(activeDims, (sc[0] + sc[1] + sc[2] + sc[3] +
                               sc[4] + sc[5] + sc[6] + sc[7]) * (1.0f / 32768.0f));
}

// ---------------------------------------------------------------------------
// k4_gmask: fallback when d_ws is too small (gmask slot hosts scratch)
// ---------------------------------------------------------------------------
__global__ __launch_bounds__(256) void k4_gmask(
    const float* __restrict__ sel, float* __restrict__ gmaskOut)
{
    const int stride = gridDim.x * 256;
    for (int i4 = blockIdx.x * 256 + threadIdx.x; i4 < 6291456; i4 += stride) {
        int row = i4 / 192;
        int rem = i4 - row * 192;
        int g = rem / 24;
        float v = sel[(size_t)row * 8 + g];
        float4 gm = {v, v, v, v};
        *(float4*)(gmaskOut + (size_t)i4 * 4) = gm;
    }
}

// ---------------------------------------------------------------------------
extern "C" void kernel_launch(void* const* d_in, const int* in_sizes, int n_in,
                              void* d_out, int out_size, void* d_ws, size_t ws_size,
                              hipStream_t stream)
{
    const float* x   = (const float*)d_in[0];
    const float* w1  = (const float*)d_in[1];
    const float* b1  = (const float*)d_in[2];
    const float* lng = (const float*)d_in[3];
    const float* lnb = (const float*)d_in[4];
    const float* w2  = (const float*)d_in[5];
    const float* b2  = (const float*)d_in[6];
    const float* w3  = (const float*)d_in[7];
    const float* b3  = (const float*)d_in[8];
    const float* dw1 = (const float*)d_in[9];
    const float* db1 = (const float*)d_in[10];
    const float* dw2 = (const float*)d_in[11];
    const float* db2 = (const float*)d_in[12];
    const float* gi  = (const float*)d_in[13];

    float* out   = (float*)d_out;
    float* mask  = out;                 // [B,768] output slot
    float* gmask = out + 25165824;      // [B,768] output slot
    float* dwts  = out + 50331648;      // [B,768] output slot
    float* probs = out + 75497472;      // [B,8]
    float* sel   = out + 75759616;      // [B,8]
    float* scal  = out + 76021760;      // 11 scalars

    // mask-slot scratch (all consumed before mfma_dw2m writes mask):
    float* u1 = mask;                        // [B,256]
    float* h1 = mask + 8388608;              // [B,256]
    float* u2 = mask + 16777216;             // [B,128]

    // g1h + converted weights: prefer d_ws (frees gmask slot -> dw2m can
    // write gmask directly, dropping the k4_gmask launch)
    const size_t WS_NEED = 16777216ULL      // g1h [B,256] bf16
                         + 393216ULL * 4    // w1Th/w1Tl/dw1T/dw2T
                         + 65536ULL * 2;    // w2Th/w2Tl
    bool useWs = (d_ws != nullptr) && (ws_size >= WS_NEED);

    unsigned short *g1h, *w1Th, *w1Tl, *dw1T, *dw2T, *w2Th, *w2Tl;
    if (useWs) {
        char* wsb = (char*)d_ws;
        g1h  = (unsigned short*)(wsb);
        w1Th = (unsigned short*)(wsb + 16777216);
        w1Tl = (unsigned short*)(wsb + 16777216 + 393216);
        dw1T = (unsigned short*)(wsb + 16777216 + 393216 * 2);
        dw2T = (unsigned short*)(wsb + 16777216 + 393216 * 3);
        w2Th = (unsigned short*)(wsb + 16777216 + 393216 * 4);
        w2Tl = (unsigned short*)(wsb + 16777216 + 393216 * 4 + 65536);
    } else {
        g1h  = (unsigned short*)gmask;
        w1Th = (unsigned short*)(gmask + 4194304);
        w1Tl = (unsigned short*)(gmask + 4292608);
        dw1T = (unsigned short*)(gmask + 4390912);
        dw2T = (unsigned short*)(gmask + 4489216);
        w2Th = (unsigned short*)(gmask + 4587520);
        w2Tl = (unsigned short*)(gmask + 4603904);
    }

    cvt_wall<<<dim3(305), dim3(256), 0, stream>>>(
        w1, dw1, dw2, w2, w1Th, w1Tl, dw1T, dw2T, w2Th, w2Tl, scal);
    // x-readers back-to-back (x stays L3-resident)
    mfma_u1<<<dim3(512), dim3(256), 0, stream>>>(x, w1Th, w1Tl, u1);
    mfma_hi<0, 1><<<dim3(512), dim3(256), 0, stream>>>(
        (const void*)x, dw1T, db1, (void*)g1h, 256, 768, 2);
    // router chain
    k1_epi<<<dim3(8192), dim3(256), 0, stream>>>(u1, b1, lng, lnb, h1);
    mfma_u2<<<dim3(256), dim3(256), 0, stream>>>(h1, w2Th, w2Tl, u2);
    k3_router<<<dim3(256), dim3(128), 0, stream>>>(
        u2, w3, b3, gi, b2, probs, sel, scal);
    // dw2 GEMM with fused dwts/mask(/gmask) writes + active_dims
    mfma_dw2m<<<dim3(768), dim3(512), 0, stream>>>(
        g1h, dw2T, db2, sel, dwts, mask, useWs ? gmask : nullptr, &scal[10]);
    if (!useWs)
        k4_gmask<<<dim3(2048), dim3(256), 0, stream>>>(sel, gmask);
}

// Round 15
// 275.951 us; speedup vs baseline: 1.0435x; 1.0435x over previous
//
#include <hip/hip_runtime.h>
#include <math.h>

#define NB 32768
#define ND 768
#define NH 256
#define NG 8
#define GSZ 96

typedef __attribute__((ext_vector_type(8))) short short8_t;
typedef __attribute__((ext_vector_type(4))) float f32x4;

__device__ __forceinline__ float gelu_exact(float v) {
    return 0.5f * v * (1.0f + erff(v * 0.7071067811865475f));
}
__device__ __forceinline__ float sigmoidf_(float v) {
    return 1.0f / (1.0f + expf(-v));
}
__device__ __forceinline__ unsigned short f2bf(float f) {
    union { float f; unsigned u; } a; a.f = f;
    unsigned r = a.u + 0x7FFF + ((a.u >> 16) & 1);
    return (unsigned short)(r >> 16);
}
__device__ __forceinline__ void f2bf2(float f, unsigned short& hi, unsigned short& lo) {
    union { float f; unsigned u; } a; a.f = f;
    unsigned r = a.u + 0x7FFF + ((a.u >> 16) & 1);
    hi = (unsigned short)(r >> 16);
    union { unsigned u; float f; } hf; hf.u = (r >> 16) << 16;
    float rem = f - hf.f;
    union { float f; unsigned u; } b; b.f = rem;
    unsigned r2 = b.u + 0x7FFF + ((b.u >> 16) & 1);
    lo = (unsigned short)(r2 >> 16);
}

// ---------------------------------------------------------------------------
// cvt_wall: weight conversions + scalar zeroing (round-12 champion version).
// ---------------------------------------------------------------------------
__global__ __launch_bounds__(256) void cvt_wall(
    const float* __restrict__ w1, const float* __restrict__ dw1,
    const float* __restrict__ dw2, const float* __restrict__ w2,
    unsigned short* __restrict__ w1Th, unsigned short* __restrict__ w1Tl,
    unsigned short* __restrict__ dw1T, unsigned short* __restrict__ dw2T,
    unsigned short* __restrict__ w2Th, unsigned short* __restrict__ w2Tl,
    float* __restrict__ scal)
{
    const int b = blockIdx.x, t = threadIdx.x;
    if (b < 96) {
        int idx = b * 256 + t;
        int k8 = idx >> 8, c = idx & 255;
        short8_t h, lo;
        #pragma unroll
        for (int j = 0; j < 8; ++j) {
            unsigned short hi_, lo_;
            f2bf2(w1[(size_t)(k8 * 8 + j) * 256 + c], hi_, lo_);
            h[j] = (short)hi_; lo[j] = (short)lo_;
        }
        *(short8_t*)(w1Th + (size_t)c * 768 + k8 * 8) = h;
        *(short8_t*)(w1Tl + (size_t)c * 768 + k8 * 8) = lo;
    } else if (b < 192) {
        int idx = (b - 96) * 256 + t;
        int k8 = idx >> 8, c = idx & 255;
        short8_t h;
        #pragma unroll
        for (int j = 0; j < 8; ++j)
            h[j] = (short)f2bf(dw1[(size_t)(k8 * 8 + j) * 256 + c]);
        *(short8_t*)(dw1T + (size_t)c * 768 + k8 * 8) = h;
    } else if (b < 288) {
        int idx = (b - 192) * 256 + t;
        int k8 = idx / 768, c = idx - k8 * 768;
        short8_t h;
        #pragma unroll
        for (int j = 0; j < 8; ++j)
            h[j] = (short)f2bf(dw2[(size_t)(k8 * 8 + j) * 768 + c]);
        *(short8_t*)(dw2T + (size_t)c * 256 + k8 * 8) = h;
    } else if (b < 304) {
        int idx = (b - 288) * 256 + t;
        int k8 = idx >> 7, c = idx & 127;
        short8_t h, lo;
        #pragma unroll
        for (int j = 0; j < 8; ++j) {
            unsigned short hi_, lo_;
            f2bf2(w2[(size_t)(k8 * 8 + j) * 128 + c], hi_, lo_);
            h[j] = (short)hi_; lo[j] = (short)lo_;
        }
        *(short8_t*)(w2Th + (size_t)c * 256 + k8 * 8) = h;
        *(short8_t*)(w2Tl + (size_t)c * 256 + k8 * 8) = lo;
    } else {
        if (t < 11) scal[t] = 0.0f;
    }
}

// ---------------------------------------------------------------------------
// mfma_u1: u1 = x @ w1 (split-3 bf16 MFMA), f32 out, no bias.
// 256 thr = 4 waves (2x2), tile 128x128, grid 512 (2 col-blocks) -> 2 blk/CU.
// ---------------------------------------------------------------------------
__global__ __launch_bounds__(256) void mfma_u1(
    const float* __restrict__ x, const unsigned short* __restrict__ BTh,
    const unsigned short* __restrict__ BTl, float* __restrict__ u1)
{
    __shared__ unsigned short Ah[128][40];
    __shared__ unsigned short Al[128][40];
    __shared__ unsigned short Bh[128][40];
    __shared__ unsigned short Bl[128][40];

    const int tid = threadIdx.x;
    const int l = tid & 63;
    const int w = tid >> 6;
    const int wm = w >> 1, wn = w & 1;
    const int lg = l >> 4, lr = l & 15;
    const int rb = blockIdx.x >> 1;
    const int cb = blockIdx.x & 1;
    const int rowsBase = rb * 128, colBase = cb * 128;

    f32x4 acc[4][4];
    #pragma unroll
    for (int mi = 0; mi < 4; ++mi)
        #pragma unroll
        for (int ni = 0; ni < 4; ++ni) acc[mi][ni] = (f32x4){0.f, 0.f, 0.f, 0.f};

    for (int kb = 0; kb < ND; kb += 32) {
        #pragma unroll
        for (int m = 0; m < 2; ++m) {
            int flat = m * 256 + tid;
            int row = flat >> 2, seg = flat & 3;
            const float* src = x + (size_t)(rowsBase + row) * ND + kb + seg * 8;
            float4 v0 = *(const float4*)src;
            float4 v1 = *(const float4*)(src + 4);
            float f[8] = {v0.x, v0.y, v0.z, v0.w, v1.x, v1.y, v1.z, v1.w};
            short8_t ph, pl;
            #pragma unroll
            for (int j = 0; j < 8; ++j) {
                unsigned short hi_, lo_;
                f2bf2(f[j], hi_, lo_);
                ph[j] = (short)hi_; pl[j] = (short)lo_;
            }
            *(short8_t*)&Ah[row][seg * 8] = ph;
            *(short8_t*)&Al[row][seg * 8] = pl;
        }
        #pragma unroll
        for (int m = 0; m < 2; ++m) {
            int flat = m * 256 + tid;
            int col = flat >> 2, seg = flat & 3;
            size_t off = (size_t)(colBase + col) * ND + kb + seg * 8;
            *(short8_t*)&Bh[col][seg * 8] = *(const short8_t*)(BTh + off);
            *(short8_t*)&Bl[col][seg * 8] = *(const short8_t*)(BTl + off);
        }
        __syncthreads();

        short8_t afh[4], afl[4], bfh[4], bfl[4];
        #pragma unroll
        for (int mi = 0; mi < 4; ++mi) {
            afh[mi] = *(const short8_t*)&Ah[wm * 64 + mi * 16 + lr][lg * 8];
            afl[mi] = *(const short8_t*)&Al[wm * 64 + mi * 16 + lr][lg * 8];
        }
        #pragma unroll
        for (int ni = 0; ni < 4; ++ni) {
            bfh[ni] = *(const short8_t*)&Bh[wn * 64 + ni * 16 + lr][lg * 8];
            bfl[ni] = *(const short8_t*)&Bl[wn * 64 + ni * 16 + lr][lg * 8];
        }
        #pragma unroll
        for (int mi = 0; mi < 4; ++mi)
            #pragma unroll
            for (int ni = 0; ni < 4; ++ni) {
                acc[mi][ni] = __builtin_amdgcn_mfma_f32_16x16x32_bf16(
                    afl[mi], bfh[ni], acc[mi][ni], 0, 0, 0);
                acc[mi][ni] = __builtin_amdgcn_mfma_f32_16x16x32_bf16(
                    afh[mi], bfl[ni], acc[mi][ni], 0, 0, 0);
                acc[mi][ni] = __builtin_amdgcn_mfma_f32_16x16x32_bf16(
                    afh[mi], bfh[ni], acc[mi][ni], 0, 0, 0);
            }
        __syncthreads();
    }

    #pragma unroll
    for (int ni = 0; ni < 4; ++ni) {
        int col = colBase + wn * 64 + ni * 16 + lr;
        #pragma unroll
        for (int mi = 0; mi < 4; ++mi) {
            int rbase = rowsBase + wm * 64 + mi * 16 + lg * 4;
            #pragma unroll
            for (int j = 0; j < 4; ++j)
                u1[(size_t)(rbase + j) * 256 + col] = acc[mi][ni][j];
        }
    }
}

// ---------------------------------------------------------------------------
// k1_epi: h1 = gelu(LN(u1 + b1)); one wave per row
// ---------------------------------------------------------------------------
__global__ __launch_bounds__(256) void k1_epi(
    const float* __restrict__ u1, const float* __restrict__ b1,
    const float* __restrict__ lng, const float* __restrict__ lnb,
    float* __restrict__ h1)
{
    const int wv = threadIdx.x >> 6, l = threadIdx.x & 63;
    const int row = blockIdx.x * 4 + wv;
    float4 a = *(const float4*)(u1 + (size_t)row * 256 + l * 4);
    float4 bb = *(const float4*)(b1 + l * 4);
    float u[4] = {a.x + bb.x, a.y + bb.y, a.z + bb.z, a.w + bb.w};
    float s = u[0] + u[1] + u[2] + u[3];
    float q = u[0]*u[0] + u[1]*u[1] + u[2]*u[2] + u[3]*u[3];
    #pragma unroll
    for (int o = 1; o < 64; o <<= 1) {
        s += __shfl_xor(s, o);
        q += __shfl_xor(q, o);
    }
    float mean = s * (1.0f / 256.0f);
    float var  = q * (1.0f / 256.0f) - mean * mean;
    float rstd = rsqrtf(var + 1e-5f);
    float4 g = *(const float4*)(lng + l * 4);
    float4 be = *(const float4*)(lnb + l * 4);
    float4 o;
    o.x = gelu_exact((u[0] - mean) * rstd * g.x + be.x);
    o.y = gelu_exact((u[1] - mean) * rstd * g.y + be.y);
    o.z = gelu_exact((u[2] - mean) * rstd * g.z + be.z);
    o.w = gelu_exact((u[3] - mean) * rstd * g.w + be.w);
    *(float4*)(h1 + (size_t)row * 256 + l * 4) = o;
}

// ---------------------------------------------------------------------------
// mfma_u2: u2 = h1 @ w2 (split-3), f32 out, no bias
// ---------------------------------------------------------------------------
__global__ __launch_bounds__(256) void mfma_u2(
    const float* __restrict__ h1, const unsigned short* __restrict__ BTh,
    const unsigned short* __restrict__ BTl, float* __restrict__ u2)
{
    __shared__ unsigned short Ah[128][40];
    __shared__ unsigned short Al[128][40];
    __shared__ unsigned short Bh[128][40];
    __shared__ unsigned short Bl[128][40];

    const int tid = threadIdx.x;
    const int l = tid & 63;
    const int w = tid >> 6;
    const int wm = w >> 1, wn = w & 1;
    const int lg = l >> 4, lr = l & 15;
    const int rowsBase = blockIdx.x * 128;

    f32x4 acc[4][4];
    #pragma unroll
    for (int mi = 0; mi < 4; ++mi)
        #pragma unroll
        for (int ni = 0; ni < 4; ++ni) acc[mi][ni] = (f32x4){0.f, 0.f, 0.f, 0.f};

    for (int kb = 0; kb < 256; kb += 32) {
        #pragma unroll
        for (int m = 0; m < 2; ++m) {
            int flat = m * 256 + tid;
            int row = flat >> 2, seg = flat & 3;
            const float* src = h1 + (size_t)(rowsBase + row) * 256 + kb + seg * 8;
            float4 v0 = *(const float4*)src;
            float4 v1 = *(const float4*)(src + 4);
            float f[8] = {v0.x, v0.y, v0.z, v0.w, v1.x, v1.y, v1.z, v1.w};
            short8_t ph, pl;
            #pragma unroll
            for (int j = 0; j < 8; ++j) {
                unsigned short hi_, lo_;
                f2bf2(f[j], hi_, lo_);
                ph[j] = (short)hi_; pl[j] = (short)lo_;
            }
            *(short8_t*)&Ah[row][seg * 8] = ph;
            *(short8_t*)&Al[row][seg * 8] = pl;
        }
        #pragma unroll
        for (int m = 0; m < 2; ++m) {
            int flat = m * 256 + tid;
            int col = flat >> 2, seg = flat & 3;
            size_t off = (size_t)col * 256 + kb + seg * 8;
            *(short8_t*)&Bh[col][seg * 8] = *(const short8_t*)(BTh + off);
            *(short8_t*)&Bl[col][seg * 8] = *(const short8_t*)(BTl + off);
        }
        __syncthreads();

        short8_t afh[4], afl[4], bfh[4], bfl[4];
        #pragma unroll
        for (int mi = 0; mi < 4; ++mi) {
            afh[mi] = *(const short8_t*)&Ah[wm * 64 + mi * 16 + lr][lg * 8];
            afl[mi] = *(const short8_t*)&Al[wm * 64 + mi * 16 + lr][lg * 8];
        }
        #pragma unroll
        for (int ni = 0; ni < 4; ++ni) {
            bfh[ni] = *(const short8_t*)&Bh[wn * 64 + ni * 16 + lr][lg * 8];
            bfl[ni] = *(const short8_t*)&Bl[wn * 64 + ni * 16 + lr][lg * 8];
        }
        #pragma unroll
        for (int mi = 0; mi < 4; ++mi)
            #pragma unroll
            for (int ni = 0; ni < 4; ++ni) {
                acc[mi][ni] = __builtin_amdgcn_mfma_f32_16x16x32_bf16(
                    afl[mi], bfh[ni], acc[mi][ni], 0, 0, 0);
                acc[mi][ni] = __builtin_amdgcn_mfma_f32_16x16x32_bf16(
                    afh[mi], bfl[ni], acc[mi][ni], 0, 0, 0);
                acc[mi][ni] = __builtin_amdgcn_mfma_f32_16x16x32_bf16(
                    afh[mi], bfh[ni], acc[mi][ni], 0, 0, 0);
            }
        __syncthreads();
    }

    #pragma unroll
    for (int ni = 0; ni < 4; ++ni) {
        int col = wn * 64 + ni * 16 + lr;
        #pragma unroll
        for (int mi = 0; mi < 4; ++mi) {
            int rbase = rowsBase + wm * 64 + mi * 16 + lg * 4;
            #pragma unroll
            for (int j = 0; j < 4; ++j)
                u2[(size_t)(rbase + j) * 128 + col] = acc[mi][ni][j];
        }
    }
}

// ---------------------------------------------------------------------------
// mfma_hi<ACT, AF32>: out = act(A @ BT^T + bias), hi-only bf16 MFMA
// ---------------------------------------------------------------------------
template<int ACT, int AF32>
__global__ __launch_bounds__(256) void mfma_hi(
    const void* __restrict__ Ap, const unsigned short* __restrict__ BT,
    const float* __restrict__ bias, void* __restrict__ outp,
    int N, int K, int colBlocks)
{
    __shared__ unsigned short As[128][40];
    __shared__ unsigned short Bs[128][40];

    const int tid = threadIdx.x;
    const int l = tid & 63;
    const int w = tid >> 6;
    const int wm = w >> 1, wn = w & 1;
    const int lg = l >> 4, lr = l & 15;
    const int rb = blockIdx.x / colBlocks;
    const int cb = blockIdx.x - rb * colBlocks;
    const int rowsBase = rb * 128, colBase = cb * 128;

    f32x4 acc[4][4];
    #pragma unroll
    for (int mi = 0; mi < 4; ++mi)
        #pragma unroll
        for (int ni = 0; ni < 4; ++ni) acc[mi][ni] = (f32x4){0.f, 0.f, 0.f, 0.f};

    for (int kb = 0; kb < K; kb += 32) {
        if (AF32) {
            const float* A = (const float*)Ap;
            #pragma unroll
            for (int m = 0; m < 2; ++m) {
                int flat = m * 256 + tid;
                int row = flat >> 2, seg = flat & 3;
                const float* src = A + (size_t)(rowsBase + row) * K + kb + seg * 8;
                float4 v0 = *(const float4*)src;
                float4 v1 = *(const float4*)(src + 4);
                float f[8] = {v0.x, v0.y, v0.z, v0.w, v1.x, v1.y, v1.z, v1.w};
                short8_t h;
                #pragma unroll
                for (int j = 0; j < 8; ++j) h[j] = (short)f2bf(f[j]);
                *(short8_t*)&As[row][seg * 8] = h;
            }
        } else {
            const unsigned short* A = (const unsigned short*)Ap;
            #pragma unroll
            for (int m = 0; m < 2; ++m) {
                int flat = m * 256 + tid;
                int row = flat >> 2, seg = flat & 3;
                *(short8_t*)&As[row][seg * 8] =
                    *(const short8_t*)(A + (size_t)(rowsBase + row) * K + kb + seg * 8);
            }
        }
        #pragma unroll
        for (int m = 0; m < 2; ++m) {
            int flat = m * 256 + tid;
            int col = flat >> 2, seg = flat & 3;
            *(short8_t*)&Bs[col][seg * 8] =
                *(const short8_t*)(BT + (size_t)(colBase + col) * K + kb + seg * 8);
        }
        __syncthreads();

        short8_t af[4], bf[4];
        #pragma unroll
        for (int mi = 0; mi < 4; ++mi)
            af[mi] = *(const short8_t*)&As[wm * 64 + mi * 16 + lr][lg * 8];
        #pragma unroll
        for (int ni = 0; ni < 4; ++ni)
            bf[ni] = *(const short8_t*)&Bs[wn * 64 + ni * 16 + lr][lg * 8];
        #pragma unroll
        for (int mi = 0; mi < 4; ++mi)
            #pragma unroll
            for (int ni = 0; ni < 4; ++ni)
                acc[mi][ni] = __builtin_amdgcn_mfma_f32_16x16x32_bf16(
                    af[mi], bf[ni], acc[mi][ni], 0, 0, 0);
        __syncthreads();
    }

    #pragma unroll
    for (int ni = 0; ni < 4; ++ni) {
        int col = colBase + wn * 64 + ni * 16 + lr;
        float bv = bias[col];
        #pragma unroll
        for (int mi = 0; mi < 4; ++mi) {
            int rbase = rowsBase + wm * 64 + mi * 16 + lg * 4;
            #pragma unroll
            for (int j = 0; j < 4; ++j) {
                float v = acc[mi][ni][j] + bv;
                if (ACT == 0) {
                    ((unsigned short*)outp)[(size_t)(rbase + j) * N + col] =
                        f2bf(gelu_exact(v));
                } else {
                    ((float*)outp)[(size_t)(rbase + j) * N + col] = sigmoidf_(v);
                }
            }
        }
    }
}

// ---------------------------------------------------------------------------
// k3: h2 = gelu(u2+b2) in-reg; logits; probs; selection -> sel; scalars
// ---------------------------------------------------------------------------
__global__ __launch_bounds__(128) void k3_router(
    const float* __restrict__ u2, const float* __restrict__ w3,
    const float* __restrict__ b3, const float* __restrict__ gi,
    const float* __restrict__ b2, float* __restrict__ probsOut,
    float* __restrict__ selOut, float* __restrict__ scal)
{
    __shared__ float ws3[128][8];
    __shared__ float sAct[2], sP[2], sCnt[2][8];

    const int tid = threadIdx.x;
    *(float4*)&ws3[tid][0] = *(const float4*)(w3 + tid * 8);
    *(float4*)&ws3[tid][4] = *(const float4*)(w3 + tid * 8 + 4);
    __syncthreads();

    const int row = blockIdx.x * 128 + tid;
    const float* r0p = u2 + (size_t)row * 128;

    float accg[8];
    #pragma unroll
    for (int g = 0; g < 8; ++g) accg[g] = 0.0f;
    #pragma unroll 4
    for (int k4 = 0; k4 < 32; ++k4) {
        float4 a = *(const float4*)(r0p + k4 * 4);
        float4 bb = *(const float4*)(b2 + k4 * 4);
        float hv4[4];
        hv4[0] = gelu_exact(a.x + bb.x);
        hv4[1] = gelu_exact(a.y + bb.y);
        hv4[2] = gelu_exact(a.z + bb.z);
        hv4[3] = gelu_exact(a.w + bb.w);
        #pragma unroll
        for (int t = 0; t < 4; ++t)
            #pragma unroll
            for (int g = 0; g < 8; ++g)
                accg[g] = fmaf(hv4[t], ws3[k4 * 4 + t][g], accg[g]);
    }

    float p[8], gs[8], cnt[8];
    float actCnt = 0.0f, pSum = 0.0f;
    #pragma unroll
    for (int g = 0; g < 8; ++g) {
        float lg = accg[g] + b3[g] + gi[g];
        p[g] = sigmoidf_(lg);
    }
    #pragma unroll
    for (int g = 0; g < 8; ++g) {
        int rank = 0;
        #pragma unroll
        for (int j = 0; j < 8; ++j) {
            rank += (p[j] > p[g]) ? 1 : 0;
            rank += (j < g && p[j] == p[g]) ? 1 : 0;
        }
        float act = (rank < 2) ? 1.0f
                  : ((rank < 6) ? ((p[g] > 0.5f) ? 1.0f : 0.0f) : 0.0f);
        gs[g] = (act - p[g]) + p[g];
        float over = (p[g] > 0.5f) ? 1.0f : 0.0f;
        cnt[g] = over;
        actCnt += over;
        pSum += p[g];
    }

    *(float4*)(probsOut + (size_t)row * 8)     = *(float4*)&p[0];
    *(float4*)(probsOut + (size_t)row * 8 + 4) = *(float4*)&p[4];
    *(float4*)(selOut   + (size_t)row * 8)     = *(float4*)&gs[0];
    *(float4*)(selOut   + (size_t)row * 8 + 4) = *(float4*)&gs[4];

    #pragma unroll
    for (int o = 32; o > 0; o >>= 1) {
        actCnt += __shfl_down(actCnt, o);
        pSum   += __shfl_down(pSum, o);
        #pragma unroll
        for (int g = 0; g < 8; ++g) cnt[g] += __shfl_down(cnt[g], o);
    }
    if ((tid & 63) == 0) {
        int w = tid >> 6;
        sAct[w] = actCnt; sP[w] = pSum;
        #pragma unroll
        for (int g = 0; g < 8; ++g) sCnt[w][g] = cnt[g];
    }
    __syncthreads();
    if (tid == 0) {
        const float invB = 1.0f / 32768.0f;
        atomicAdd(&scal[0], (sAct[0] + sAct[1]) * invB);
        atomicAdd(&scal[9], (sP[0] + sP[1]) * invB);
        #pragma unroll
        for (int g = 0; g < 8; ++g)
            atomicAdd(&scal[1 + g], (sCnt[0][g] + sCnt[1][g]) * invB);
    }
}

// ---------------------------------------------------------------------------
// mfma_dw2m: dwts = sigmoid(g1h @ dw2 + db2), mask = sel_rep * dwts,
// active_dims count, fused. 512 thr, tile 128x256, grid 768.
// ---------------------------------------------------------------------------
__global__ __launch_bounds__(512) void mfma_dw2m(
    const unsigned short* __restrict__ g1h, const unsigned short* __restrict__ dw2T,
    const float* __restrict__ db2, const float* __restrict__ sel,
    float* __restrict__ dwts, float* __restrict__ maskOut,
    float* __restrict__ activeDims)
{
    __shared__ unsigned short As[128][40];
    __shared__ unsigned short Bs[256][40];
    __shared__ float sc[8];

    const int tid = threadIdx.x;
    const int l = tid & 63;
    const int w = tid >> 6;
    const int wm = w >> 2, wn = w & 3;
    const int lg = l >> 4, lr = l & 15;
    const int rb = blockIdx.x / 3, cb = blockIdx.x - rb * 3;
    const int rowsBase = rb * 128, colBase = cb * 256;

    f32x4 acc[4][4];
    #pragma unroll
    for (int mi = 0; mi < 4; ++mi)
        #pragma unroll
        for (int ni = 0; ni < 4; ++ni) acc[mi][ni] = (f32x4){0.f, 0.f, 0.f, 0.f};

    const int sArow = tid >> 2, sAseg = tid & 3;

    for (int kb = 0; kb < 256; kb += 32) {
        *(short8_t*)&As[sArow][sAseg * 8] =
            *(const short8_t*)(g1h + (size_t)(rowsBase + sArow) * 256 + kb + sAseg * 8);
        #pragma unroll
        for (int m = 0; m < 2; ++m) {
            int flat = m * 512 + tid;
            int col = flat >> 2, seg = flat & 3;
            *(short8_t*)&Bs[col][seg * 8] =
                *(const short8_t*)(dw2T + (size_t)(colBase + col) * 256 + kb + seg * 8);
        }
        __syncthreads();

        short8_t af[4], bf[4];
        #pragma unroll
        for (int mi = 0; mi < 4; ++mi)
            af[mi] = *(const short8_t*)&As[wm * 64 + mi * 16 + lr][lg * 8];
        #pragma unroll
        for (int ni = 0; ni < 4; ++ni)
            bf[ni] = *(const short8_t*)&Bs[wn * 64 + ni * 16 + lr][lg * 8];
        #pragma unroll
        for (int mi = 0; mi < 4; ++mi)
            #pragma unroll
            for (int ni = 0; ni < 4; ++ni)
                acc[mi][ni] = __builtin_amdgcn_mfma_f32_16x16x32_bf16(
                    af[mi], bf[ni], acc[mi][ni], 0, 0, 0);
        __syncthreads();
    }

    float cntF = 0.0f;
    #pragma unroll
    for (int ni = 0; ni < 4; ++ni) {
        int col = colBase + wn * 64 + ni * 16 + lr;
        float bv = db2[col];
        int g = col / GSZ;
        #pragma unroll
        for (int mi = 0; mi < 4; ++mi) {
            int rbase = rowsBase + wm * 64 + mi * 16 + lg * 4;
            #pragma unroll
            for (int j = 0; j < 4; ++j) {
                int row = rbase + j;
                float v = sigmoidf_(acc[mi][ni][j] + bv);
                dwts[(size_t)row * 768 + col] = v;
                float m = sel[(size_t)row * 8 + g] * v;
                maskOut[(size_t)row * 768 + col] = m;
                cntF += (m > 0.5f) ? 1.0f : 0.0f;
            }
        }
    }
    #pragma unroll
    for (int o = 32; o > 0; o >>= 1) cntF += __shfl_down(cntF, o);
    if ((tid & 63) == 0) sc[tid >> 6] = cntF;
    __syncthreads();
    if (tid == 0)
        atomicAdd(activeDims, (sc[0] + sc[1] + sc[2] + sc[3] +
                               sc[4] + sc[5] + sc[6] + sc[7]) * (1.0f / 32768.0f));
}

// ---------------------------------------------------------------------------
// k4_gmask: gmask = repeat(sel) (coalesced float4 writes, overlaps dw2m drain)
// ---------------------------------------------------------------------------
__global__ __launch_bounds__(256) void k4_gmask(
    const float* __restrict__ sel, float* __restrict__ gmaskOut)
{
    const int stride = gridDim.x * 256;
    for (int i4 = blockIdx.x * 256 + threadIdx.x; i4 < 6291456; i4 += stride) {
        int row = i4 / 192;
        int rem = i4 - row * 192;
        int g = rem / 24;
        float v = sel[(size_t)row * 8 + g];
        float4 gm = {v, v, v, v};
        *(float4*)(gmaskOut + (size_t)i4 * 4) = gm;
    }
}

// ---------------------------------------------------------------------------
extern "C" void kernel_launch(void* const* d_in, const int* in_sizes, int n_in,
                              void* d_out, int out_size, void* d_ws, size_t ws_size,
                              hipStream_t stream)
{
    const float* x   = (const float*)d_in[0];
    const float* w1  = (const float*)d_in[1];
    const float* b1  = (const float*)d_in[2];
    const float* lng = (const float*)d_in[3];
    const float* lnb = (const float*)d_in[4];
    const float* w2  = (const float*)d_in[5];
    const float* b2  = (const float*)d_in[6];
    const float* w3  = (const float*)d_in[7];
    const float* b3  = (const float*)d_in[8];
    const float* dw1 = (const float*)d_in[9];
    const float* db1 = (const float*)d_in[10];
    const float* dw2 = (const float*)d_in[11];
    const float* db2 = (const float*)d_in[12];
    const float* gi  = (const float*)d_in[13];

    float* out   = (float*)d_out;
    float* mask  = out;                 // [B,768] output slot
    float* gmask = out + 25165824;      // [B,768] output slot
    float* dwts  = out + 50331648;      // [B,768] output slot
    float* probs = out + 75497472;      // [B,8]
    float* sel   = out + 75759616;      // [B,8]
    float* scal  = out + 76021760;      // 11 scalars

    // scratch in dead output slots (round-12 champion layout):
    // mask slot: u1 [B,256] + h1 [B,256] + u2 [B,128] — all consumed before
    // mfma_dw2m writes mask.
    float* u1 = mask;                        // 8388608 floats
    float* h1 = mask + 8388608;              // 8388608 floats
    float* u2 = mask + 16777216;             // 4194304 floats
    // gmask slot: g1h bf16 + converted weights (dead until k4_gmask, last)
    unsigned short* g1h  = (unsigned short*)gmask;                 // 4194304 f-equiv
    unsigned short* w1Th = (unsigned short*)(gmask + 4194304);     // 98304 f-equiv
    unsigned short* w1Tl = (unsigned short*)(gmask + 4292608);     // 98304
    unsigned short* dw1T = (unsigned short*)(gmask + 4390912);     // 98304
    unsigned short* dw2T = (unsigned short*)(gmask + 4489216);     // 98304
    unsigned short* w2Th = (unsigned short*)(gmask + 4587520);     // 16384
    unsigned short* w2Tl = (unsigned short*)(gmask + 4603904);     // 16384

    cvt_wall<<<dim3(305), dim3(256), 0, stream>>>(
        w1, dw1, dw2, w2, w1Th, w1Tl, dw1T, dw2T, w2Th, w2Tl, scal);
    // x-readers back-to-back: x (100 MB) stays L3-resident across both
    mfma_u1<<<dim3(512), dim3(256), 0, stream>>>(x, w1Th, w1Tl, u1);
    mfma_hi<0, 1><<<dim3(512), dim3(256), 0, stream>>>(
        (const void*)x, dw1T, db1, (void*)g1h, 256, 768, 2);
    // router chain
    k1_epi<<<dim3(8192), dim3(256), 0, stream>>>(u1, b1, lng, lnb, h1);
    mfma_u2<<<dim3(256), dim3(256), 0, stream>>>(h1, w2Th, w2Tl, u2);
    k3_router<<<dim3(256), dim3(128), 0, stream>>>(
        u2, w3, b3, gi, b2, probs, sel, scal);
    // dw2 GEMM with fused dwts/mask writes + active_dims (needs sel)
    mfma_dw2m<<<dim3(768), dim3(512), 0, stream>>>(
        g1h, dw2T, db2, sel, dwts, mask, &scal[10]);
    // gmask last (its slot hosted g1h/weights until mfma_dw2m finished)
    k4_gmask<<<dim3(2048), dim3(256), 0, stream>>>(sel, gmask);
}